// Round 4
// baseline (758.042 us; speedup 1.0000x reference)
//
#include <hip/hip_runtime.h>
#include <hip/hip_bf16.h>

// TSA loss for MI355X.
// loss = mean((outputs-targets)^2) + 0.1 * mean_b( || Pz_b - Px_b ||_F^2 )
// where Pz/Px are rank-1 projectors onto the top eigenvector of the 25-NN
// covariance of latent/raw. Using ||uu^T - vv^T||^2 = 2(1-(u.v)^2), the Gram
// trick (25x25 instead of 64x64), double-centering of the Gram, and top
// eigenvector via 12 trace-normalized matrix squarings (power 4096).
// d2 is chunked at 2048 rows (64 MB) so each chunk stays L3-resident.

#define NB 8192
#define ND 64
#define KSEL 26
#define ROUNDS 12

// ---------------- sq[i] = sum_d raw[i][d]^2 ; also zero recon accumulator ---
__global__ __launch_bounds__(256) void tsa_sq_kernel(const float* __restrict__ raw,
                                                     float* __restrict__ sq,
                                                     float* __restrict__ reconS) {
    int row = blockIdx.x * 4 + (threadIdx.x >> 6);
    int lane = threadIdx.x & 63;
    float v = raw[row * 64 + lane];
    float s = v * v;
    #pragma unroll
    for (int off = 1; off < 64; off <<= 1) s += __shfl_xor(s, off);
    if (lane == 0) sq[row] = s;
    if (blockIdx.x == 0 && threadIdx.x == 0) reconS[0] = 0.0f;
}

// ---------------- rawT[k][i] = raw[i][k] (64 x 8192) ------------------------
__global__ __launch_bounds__(256) void tsa_transpose_kernel(const float* __restrict__ raw,
                                                            float* __restrict__ rawT) {
    __shared__ float tile[64][65];
    int t = threadIdx.x;
    int r0 = blockIdx.x * 64;
    #pragma unroll
    for (int r = 0; r < 4; ++r) {
        int e = r * 256 + t;
        int m = e >> 4, c4 = e & 15;
        float4 v = ((const float4*)raw)[(r0 + m) * 16 + c4];
        tile[m][c4 * 4 + 0] = v.x; tile[m][c4 * 4 + 1] = v.y;
        tile[m][c4 * 4 + 2] = v.z; tile[m][c4 * 4 + 3] = v.w;
    }
    __syncthreads();
    #pragma unroll
    for (int r = 0; r < 4; ++r) {
        int e = r * 256 + t;
        int k = e >> 4, c4 = e & 15;
        float4 v;
        v.x = tile[c4 * 4 + 0][k]; v.y = tile[c4 * 4 + 1][k];
        v.z = tile[c4 * 4 + 2][k]; v.w = tile[c4 * 4 + 3][k];
        ((float4*)rawT)[k * 2048 + (r0 >> 2) + c4] = v;
    }
}

// ---------------- recon partial sums (atomicAdd raw sum) --------------------
__global__ __launch_bounds__(256) void tsa_recon_kernel(const float* __restrict__ o,
                                                        const float* __restrict__ tg,
                                                        float* __restrict__ reconS) {
    int idx = blockIdx.x * 256 + threadIdx.x;
    float4 a = ((const float4*)o)[idx];
    float4 b = ((const float4*)tg)[idx];
    float dx = a.x - b.x, dy = a.y - b.y, dz = a.z - b.z, dw = a.w - b.w;
    float s = dx * dx + dy * dy + dz * dz + dw * dw;
    #pragma unroll
    for (int off = 1; off < 64; off <<= 1) s += __shfl_xor(s, off);
    __shared__ float ps[4];
    if ((threadIdx.x & 63) == 0) ps[threadIdx.x >> 6] = s;
    __syncthreads();
    if (threadIdx.x == 0) atomicAdd(reconS, ps[0] + ps[1] + ps[2] + ps[3]);
}

// ---------------- distance tile GEMM: d2[i][j] = sq[i]+sq[j]-2*dot ----------
// 128x128 tile, 256 threads, 8x8 per thread, K=64 single shot.
__global__ __launch_bounds__(256) void tsa_dist_kernel(const float* __restrict__ rawT,
                                                       const float* __restrict__ sq,
                                                       float* __restrict__ d2,
                                                       int rowBase) {
    __shared__ float At[64 * 128];
    __shared__ float Bt[64 * 128];
    const int t = threadIdx.x;
    const int m0 = rowBase + blockIdx.y * 128;
    const int n0 = blockIdx.x * 128;
    const float4* rT4 = (const float4*)rawT;
    float4* At4 = (float4*)At;
    float4* Bt4 = (float4*)Bt;
    #pragma unroll
    for (int r = 0; r < 8; ++r) {
        int e = r * 256 + t;
        int k = e >> 5, c = e & 31;
        At4[e] = rT4[k * 2048 + (m0 >> 2) + c];
        Bt4[e] = rT4[k * 2048 + (n0 >> 2) + c];
    }
    __syncthreads();
    const int tx = t >> 4;   // m-block (rows)
    const int ty = t & 15;   // n-block (cols, fast for coalesced stores)
    float acc[8][8];
    #pragma unroll
    for (int i = 0; i < 8; ++i)
        #pragma unroll
        for (int j = 0; j < 8; ++j) acc[i][j] = 0.0f;

    #pragma unroll 4
    for (int k = 0; k < 64; ++k) {
        float4 a0 = At4[k * 32 + tx * 2 + 0];
        float4 a1 = At4[k * 32 + tx * 2 + 1];
        float4 b0 = Bt4[k * 32 + ty];
        float4 b1 = Bt4[k * 32 + 16 + ty];
        float av[8] = {a0.x, a0.y, a0.z, a0.w, a1.x, a1.y, a1.z, a1.w};
        float bw[8] = {b0.x, b0.y, b0.z, b0.w, b1.x, b1.y, b1.z, b1.w};
        #pragma unroll
        for (int i = 0; i < 8; ++i)
            #pragma unroll
            for (int j = 0; j < 8; ++j)
                acc[i][j] += av[i] * bw[j];
    }
    float sqm[8], sqn[8];
    #pragma unroll
    for (int i = 0; i < 8; ++i) sqm[i] = sq[m0 + tx * 8 + i];
    #pragma unroll
    for (int j = 0; j < 4; ++j) {
        sqn[j]     = sq[n0 + ty * 4 + j];
        sqn[4 + j] = sq[n0 + 64 + ty * 4 + j];
    }
    #pragma unroll
    for (int i = 0; i < 8; ++i) {
        size_t rowoff = (size_t)(m0 - rowBase + tx * 8 + i) * 8192;
        float4 w0, w1;
        w0.x = sqm[i] + sqn[0] - 2.0f * acc[i][0];
        w0.y = sqm[i] + sqn[1] - 2.0f * acc[i][1];
        w0.z = sqm[i] + sqn[2] - 2.0f * acc[i][2];
        w0.w = sqm[i] + sqn[3] - 2.0f * acc[i][3];
        w1.x = sqm[i] + sqn[4] - 2.0f * acc[i][4];
        w1.y = sqm[i] + sqn[5] - 2.0f * acc[i][5];
        w1.z = sqm[i] + sqn[6] - 2.0f * acc[i][6];
        w1.w = sqm[i] + sqn[7] - 2.0f * acc[i][7];
        float4* wp = (float4*)(d2 + rowoff + n0);
        wp[ty] = w0;
        wp[16 + ty] = w1;
    }
}

// ---------------- per-row selection of 26 smallest, drop rank-0 -------------
// 4 waves: each wave finds top-26 of its 2048 elems (registers, wave-sync,
// no barriers), then wave 0 merges 104 candidates. Tie-break: smaller index.
__global__ __launch_bounds__(256) void tsa_select_kernel(const float* __restrict__ d2,
                                                         int* __restrict__ nbrs,
                                                         int rowBase) {
    const int t = threadIdx.x;
    const int lane = t & 63;
    const int wv = t >> 6;
    const int i = rowBase + blockIdx.x;
    const float4* row4 = (const float4*)(d2 + (size_t)blockIdx.x * 8192u);

    float v[32];
    #pragma unroll
    for (int r = 0; r < 8; ++r) {
        float4 f = row4[wv * 512 + r * 64 + lane];
        v[4 * r + 0] = f.x; v[4 * r + 1] = f.y;
        v[4 * r + 2] = f.z; v[4 * r + 3] = f.w;
    }
    __shared__ float selV[4][KSEL];
    __shared__ int   selJ[4][KSEL];
    unsigned removed = 0;
    for (int round = 0; round < KSEL; ++round) {
        float bv = 3.0e38f; int bq = 0;
        #pragma unroll
        for (int q = 0; q < 32; ++q) {
            bool ok = ((removed >> q) & 1u) == 0u;
            bool c = ok && (v[q] < bv);
            bv = c ? v[q] : bv;
            bq = c ? q : bq;
        }
        int bj = wv * 2048 + (bq >> 2) * 256 + lane * 4 + (bq & 3);
        #pragma unroll
        for (int off = 1; off < 64; off <<= 1) {
            float rv = __shfl_xor(bv, off);
            int rj = __shfl_xor(bj, off);
            bool take = (rv < bv) || (rv == bv && rj < bj);
            bv = take ? rv : bv;
            bj = take ? rj : bj;
        }
        int jl = bj - wv * 2048;
        int ol = (jl >> 2) & 63;
        int oq = ((jl >> 8) << 2) | (jl & 3);
        if (lane == ol) removed |= (1u << oq);
        if (lane == 0) { selV[wv][round] = bv; selJ[wv][round] = bj; }
    }
    __syncthreads();
    if (wv == 0) {
        bool has = lane < 52;
        int p0 = lane, p1 = lane + 52;
        float v0 = has ? selV[p0 / KSEL][p0 % KSEL] : 3.0e38f;
        int   j0 = has ? selJ[p0 / KSEL][p0 % KSEL] : 0x7ffffffe;
        float v1 = has ? selV[p1 / KSEL][p1 % KSEL] : 3.0e38f;
        int   j1 = has ? selJ[p1 / KSEL][p1 % KSEL] : 0x7ffffffe;
        unsigned rm = 0;
        for (int round = 0; round < KSEL; ++round) {
            float bv = 3.0e38f; int bj = 0x7fffffff;
            if (!(rm & 1u)) { bv = v0; bj = j0; }
            if (!(rm & 2u) && (v1 < bv || (v1 == bv && j1 < bj))) { bv = v1; bj = j1; }
            #pragma unroll
            for (int off = 1; off < 64; off <<= 1) {
                float rv = __shfl_xor(bv, off);
                int rj = __shfl_xor(bj, off);
                bool take = (rv < bv) || (rv == bv && rj < bj);
                bv = take ? rv : bv;
                bj = take ? rj : bj;
            }
            if (bv == v0 && bj == j0) rm |= 1u;
            else if (bv == v1 && bj == j1) rm |= 2u;
            if (lane == 0 && round > 0) nbrs[i * 25 + round - 1] = bj;
        }
    }
}

// ---------------- per-sample eigen + per_sample value -----------------------
// 4 rows per block, one wave per row. Within a wave: lanes 0..24 own columns
// of Gz (latent gram), lanes 32..56 own columns of Gx (raw gram). Columns
// live in registers; LDS used only for row/column broadcasts.
__global__ __launch_bounds__(256) void tsa_eigen_kernel(const int* __restrict__ nbrs,
                                                        const float* __restrict__ latent,
                                                        const float* __restrict__ raw,
                                                        float* __restrict__ tsaV) {
    __shared__ float zx[4][2][25][68];   // staged neighbor rows (Z then X)
    __shared__ float gt[4][2][25][28];   // gram columns for broadcast
    __shared__ float rsb[4][2][32];      // row sums
    __shared__ int   jm_s[4][2];
    const int t = threadIdx.x, lane = t & 63, wv = t >> 6;
    const int i = blockIdx.x * 4 + wv;
    const int half = lane >> 5;
    const int b = lane & 31;
    const bool act = b < 25;
    const int bb = act ? b : 0;
    const float* src = half ? raw : latent;

    if (act) {
        int nb = nbrs[i * 25 + b];
        const float4* s4 = (const float4*)(src + nb * 64);
        float4* dst = (float4*)&zx[wv][half][b][0];
        #pragma unroll
        for (int c = 0; c < 16; ++c) dst[c] = s4[c];
    }
    __syncthreads();

    // Gram: g[a] = dot(row a, own row b)  (64-long dot, 16-float chunks)
    float g[25];
    #pragma unroll
    for (int a = 0; a < 25; ++a) g[a] = 0.0f;
    #pragma unroll 1
    for (int ch = 0; ch < 4; ++ch) {
        float ow[16];
        const float4* op = (const float4*)&zx[wv][half][bb][0];
        ((float4*)ow)[0] = op[ch * 4 + 0];
        ((float4*)ow)[1] = op[ch * 4 + 1];
        ((float4*)ow)[2] = op[ch * 4 + 2];
        ((float4*)ow)[3] = op[ch * 4 + 3];
        #pragma unroll
        for (int a = 0; a < 25; ++a) {
            float rr[16];
            const float4* rp = (const float4*)&zx[wv][half][a][0];
            ((float4*)rr)[0] = rp[ch * 4 + 0];
            ((float4*)rr)[1] = rp[ch * 4 + 1];
            ((float4*)rr)[2] = rp[ch * 4 + 2];
            ((float4*)rr)[3] = rp[ch * 4 + 3];
            float s = 0.0f;
            #pragma unroll
            for (int d4 = 0; d4 < 16; ++d4) s += ow[d4] * rr[d4];
            g[a] += s;
        }
    }

    // Double-centering: Gc = G - rowmean[a] - rowmean[b] + grandmean
    {
        float rs_own = 0.0f;
        #pragma unroll
        for (int a = 0; a < 25; ++a) rs_own += g[a];
        if (act) rsb[wv][half][b] = rs_own;
        __syncthreads();
        float rsA[25];
        float grand = 0.0f;
        #pragma unroll
        for (int a = 0; a < 25; ++a) { rsA[a] = rsb[wv][half][a]; grand += rsA[a]; }
        const float c1 = 1.0f / 25.0f, c2 = 1.0f / 625.0f;
        #pragma unroll
        for (int a = 0; a < 25; ++a)
            g[a] = g[a] - rsA[a] * c1 - rs_own * c1 + grand * c2;
    }

    // 12 trace-normalized squarings: g <- (G*G)/tr(G*G); tr(G^2)=||G||_F^2
    #pragma unroll 1
    for (int rd = 0; rd < ROUNDS; ++rd) {
        float ss = 0.0f;
        #pragma unroll
        for (int r2 = 0; r2 < 25; ++r2) ss += g[r2] * g[r2];
        ss = act ? ss : 0.0f;
        #pragma unroll
        for (int off = 1; off < 32; off <<= 1) ss += __shfl_xor(ss, off);
        float inv = 1.0f / ss;
        if (act) {
            float4* gw = (float4*)&gt[wv][half][b][0];
            gw[0] = make_float4(g[0], g[1], g[2], g[3]);
            gw[1] = make_float4(g[4], g[5], g[6], g[7]);
            gw[2] = make_float4(g[8], g[9], g[10], g[11]);
            gw[3] = make_float4(g[12], g[13], g[14], g[15]);
            gw[4] = make_float4(g[16], g[17], g[18], g[19]);
            gw[5] = make_float4(g[20], g[21], g[22], g[23]);
            gw[6] = make_float4(g[24], 0.0f, 0.0f, 0.0f);
        }
        __syncthreads();
        float ng[25];
        #pragma unroll
        for (int r2 = 0; r2 < 25; ++r2) ng[r2] = 0.0f;
        #pragma unroll
        for (int c = 0; c < 25; ++c) {
            float cc2[28];
            const float4* gr = (const float4*)&gt[wv][half][c][0];
            ((float4*)cc2)[0] = gr[0];
            ((float4*)cc2)[1] = gr[1];
            ((float4*)cc2)[2] = gr[2];
            ((float4*)cc2)[3] = gr[3];
            ((float4*)cc2)[4] = gr[4];
            ((float4*)cc2)[5] = gr[5];
            ((float4*)cc2)[6] = gr[6];
            float m2 = g[c];
            #pragma unroll
            for (int r2 = 0; r2 < 25; ++r2) ng[r2] += cc2[r2] * m2;
        }
        #pragma unroll
        for (int r2 = 0; r2 < 25; ++r2) g[r2] = ng[r2] * inv;
        __syncthreads();
    }

    // final columns to LDS
    if (act) {
        float4* gw = (float4*)&gt[wv][half][b][0];
        gw[0] = make_float4(g[0], g[1], g[2], g[3]);
        gw[1] = make_float4(g[4], g[5], g[6], g[7]);
        gw[2] = make_float4(g[8], g[9], g[10], g[11]);
        gw[3] = make_float4(g[12], g[13], g[14], g[15]);
        gw[4] = make_float4(g[16], g[17], g[18], g[19]);
        gw[5] = make_float4(g[20], g[21], g[22], g[23]);
        gw[6] = make_float4(g[24], 0.0f, 0.0f, 0.0f);
    }
    __syncthreads();

    // argmax of diagonal per half -> best-conditioned column = eigenvector
    float dv = act ? gt[wv][half][b][b] : -1.0f;
    int bi = b;
    #pragma unroll
    for (int off = 1; off < 32; off <<= 1) {
        float ov = __shfl_xor(dv, off);
        int oi = __shfl_xor(bi, off);
        bool take = (ov > dv) || (ov == dv && oi < bi);
        dv = take ? ov : dv;
        bi = take ? oi : bi;
    }
    if (lane == 0)  jm_s[wv][0] = bi;
    if (lane == 32) jm_s[wv][1] = bi;
    __syncthreads();
    int jz = jm_s[wv][0], jxm = jm_s[wv][1];

    float wzArr[28], wxArr[28];
    {
        const float4* wz4 = (const float4*)&gt[wv][0][jz][0];
        const float4* wx4 = (const float4*)&gt[wv][1][jxm][0];
        #pragma unroll
        for (int q = 0; q < 7; ++q) {
            ((float4*)wzArr)[q] = wz4[q];
            ((float4*)wxArr)[q] = wx4[q];
        }
    }
    float szs = 0.0f, sxs = 0.0f;
    #pragma unroll
    for (int k = 0; k < 25; ++k) { szs += wzArr[k]; sxs += wxArr[k]; }
    float azc = szs * (1.0f / 25.0f), axc = sxs * (1.0f / 25.0f);

    // u[d] = sum_k Zc[k][d] w[k] = sum_k Z[k][d] (w[k]-mean(w)); lane = d
    float uz = 0.0f, ux = 0.0f;
    #pragma unroll
    for (int k = 0; k < 25; ++k) {
        uz += zx[wv][0][k][lane] * (wzArr[k] - azc);
        ux += zx[wv][1][k][lane] * (wxArr[k] - axc);
    }
    float aa = uz * uz, bbv = ux * ux, ccv = uz * ux;
    #pragma unroll
    for (int off = 1; off < 64; off <<= 1) {
        aa += __shfl_xor(aa, off);
        bbv += __shfl_xor(bbv, off);
        ccv += __shfl_xor(ccv, off);
    }
    if (lane == 0) {
        float dot2 = (ccv * ccv) / fmaxf(aa * bbv, 1e-30f);
        tsaV[i] = 2.0f - 2.0f * dot2;
    }
}

// ---------------- final: out = recon/524288 + 0.1*mean(tsaV) ----------------
__global__ __launch_bounds__(256) void tsa_final_kernel(const float* __restrict__ tsaV,
                                                        const float* __restrict__ reconS,
                                                        float* __restrict__ out) {
    float s = 0.0f;
    const float4* v4 = (const float4*)tsaV;
    for (int e = threadIdx.x; e < 2048; e += 256) {
        float4 v = v4[e];
        s += (v.x + v.y) + (v.z + v.w);
    }
    #pragma unroll
    for (int off = 1; off < 64; off <<= 1) s += __shfl_xor(s, off);
    __shared__ float ps[4];
    if ((threadIdx.x & 63) == 0) ps[threadIdx.x >> 6] = s;
    __syncthreads();
    if (threadIdx.x == 0) {
        float tot = ps[0] + ps[1] + ps[2] + ps[3];
        out[0] = reconS[0] * (1.0f / 524288.0f) + 0.1f * (tot * (1.0f / 8192.0f));
    }
}

extern "C" void kernel_launch(void* const* d_in, const int* in_sizes, int n_in,
                              void* d_out, int out_size, void* d_ws, size_t ws_size,
                              hipStream_t stream) {
    const float* outputs = (const float*)d_in[0];
    const float* targets = (const float*)d_in[1];
    const float* latent  = (const float*)d_in[2];
    const float* raw     = (const float*)d_in[3];

    float* ws = (float*)d_ws;
    // ws layout (floats), all offsets 64B-aligned:
    float* sq     = ws;                       // 8192
    float* rawT   = ws + 8192;                // 524288
    int*   nbrs   = (int*)(ws + 532480);      // 8192*25 ints
    float* reconS = ws + 737280;              // 1 (+pad)
    float* tsaV   = ws + 737296;              // 8192
    float* d2buf  = ws + 745728;              // R * 8192

    size_t availF = ws_size / 4;
    // Cap chunk at 2048 rows (64 MB) so the d2 chunk stays L3-resident;
    // halve further if the workspace is smaller.
    int R = 2048;
    while (R > 128 && (size_t)745728 + (size_t)R * 8192 > availF) R >>= 1;

    tsa_sq_kernel<<<2048, 256, 0, stream>>>(raw, sq, reconS);
    tsa_transpose_kernel<<<128, 256, 0, stream>>>(raw, rawT);
    tsa_recon_kernel<<<512, 256, 0, stream>>>(outputs, targets, reconS);

    for (int rb = 0; rb < 8192; rb += R) {
        dim3 g(64, R / 128);
        tsa_dist_kernel<<<g, 256, 0, stream>>>(rawT, sq, d2buf, rb);
        tsa_select_kernel<<<R, 256, 0, stream>>>(d2buf, nbrs, rb);
    }
    tsa_eigen_kernel<<<2048, 256, 0, stream>>>(nbrs, latent, raw, tsaV);
    tsa_final_kernel<<<1, 256, 0, stream>>>(tsaV, reconS, (float*)d_out);
}

// Round 7
// 739.624 us; speedup vs baseline: 1.0249x; 1.0249x over previous
//
#include <hip/hip_runtime.h>
#include <hip/hip_bf16.h>

// TSA loss for MI355X.
// loss = mean((outputs-targets)^2) + 0.1 * mean_b( || Pz_b - Px_b ||_F^2 )
// where Pz/Px are rank-1 projectors onto the top eigenvector of the 25-NN
// covariance of latent/raw. Using ||uu^T - vv^T||^2 = 2(1-(u.v)^2), the Gram
// trick (25x25 instead of 64x64), double-centering of the Gram, and top
// eigenvector via 8 trace-normalized matrix squarings (power 256).
// d2 is chunked at 2048 rows (64 MB) so each chunk stays L3-resident.
// Eigen kernel: barrier-free (all LDS deps are intra-wave; s_waitcnt
// lgkmcnt(0) suffices), gt aliases zx (final u re-reads rows from L2),
// 54.4 KB LDS -> 3 blocks/CU.

#define NB 8192
#define ND 64
#define KSEL 26
#define ROUNDS 8

// ---------------- sq[i] = sum_d raw[i][d]^2 ; also zero recon accumulator ---
__global__ __launch_bounds__(256) void tsa_sq_kernel(const float* __restrict__ raw,
                                                     float* __restrict__ sq,
                                                     float* __restrict__ reconS) {
    int row = blockIdx.x * 4 + (threadIdx.x >> 6);
    int lane = threadIdx.x & 63;
    float v = raw[row * 64 + lane];
    float s = v * v;
    #pragma unroll
    for (int off = 1; off < 64; off <<= 1) s += __shfl_xor(s, off);
    if (lane == 0) sq[row] = s;
    if (blockIdx.x == 0 && threadIdx.x == 0) reconS[0] = 0.0f;
}

// ---------------- rawT[k][i] = raw[i][k] (64 x 8192) ------------------------
__global__ __launch_bounds__(256) void tsa_transpose_kernel(const float* __restrict__ raw,
                                                            float* __restrict__ rawT) {
    __shared__ float tile[64][65];
    int t = threadIdx.x;
    int r0 = blockIdx.x * 64;
    #pragma unroll
    for (int r = 0; r < 4; ++r) {
        int e = r * 256 + t;
        int m = e >> 4, c4 = e & 15;
        float4 v = ((const float4*)raw)[(r0 + m) * 16 + c4];
        tile[m][c4 * 4 + 0] = v.x; tile[m][c4 * 4 + 1] = v.y;
        tile[m][c4 * 4 + 2] = v.z; tile[m][c4 * 4 + 3] = v.w;
    }
    __syncthreads();
    #pragma unroll
    for (int r = 0; r < 4; ++r) {
        int e = r * 256 + t;
        int k = e >> 4, c4 = e & 15;
        float4 v;
        v.x = tile[c4 * 4 + 0][k]; v.y = tile[c4 * 4 + 1][k];
        v.z = tile[c4 * 4 + 2][k]; v.w = tile[c4 * 4 + 3][k];
        ((float4*)rawT)[k * 2048 + (r0 >> 2) + c4] = v;
    }
}

// ---------------- recon partial sums (atomicAdd raw sum) --------------------
__global__ __launch_bounds__(256) void tsa_recon_kernel(const float* __restrict__ o,
                                                        const float* __restrict__ tg,
                                                        float* __restrict__ reconS) {
    int idx = blockIdx.x * 256 + threadIdx.x;
    float4 a = ((const float4*)o)[idx];
    float4 b = ((const float4*)tg)[idx];
    float dx = a.x - b.x, dy = a.y - b.y, dz = a.z - b.z, dw = a.w - b.w;
    float s = dx * dx + dy * dy + dz * dz + dw * dw;
    #pragma unroll
    for (int off = 1; off < 64; off <<= 1) s += __shfl_xor(s, off);
    __shared__ float ps[4];
    if ((threadIdx.x & 63) == 0) ps[threadIdx.x >> 6] = s;
    __syncthreads();
    if (threadIdx.x == 0) atomicAdd(reconS, ps[0] + ps[1] + ps[2] + ps[3]);
}

// ---------------- distance tile GEMM: d2[i][j] = sq[i]+sq[j]-2*dot ----------
// 128x128 tile, 256 threads, 8x8 per thread, K=64 single shot.
__global__ __launch_bounds__(256) void tsa_dist_kernel(const float* __restrict__ rawT,
                                                       const float* __restrict__ sq,
                                                       float* __restrict__ d2,
                                                       int rowBase) {
    __shared__ float At[64 * 128];
    __shared__ float Bt[64 * 128];
    const int t = threadIdx.x;
    const int m0 = rowBase + blockIdx.y * 128;
    const int n0 = blockIdx.x * 128;
    const float4* rT4 = (const float4*)rawT;
    float4* At4 = (float4*)At;
    float4* Bt4 = (float4*)Bt;
    #pragma unroll
    for (int r = 0; r < 8; ++r) {
        int e = r * 256 + t;
        int k = e >> 5, c = e & 31;
        At4[e] = rT4[k * 2048 + (m0 >> 2) + c];
        Bt4[e] = rT4[k * 2048 + (n0 >> 2) + c];
    }
    __syncthreads();
    const int tx = t >> 4;   // m-block (rows)
    const int ty = t & 15;   // n-block (cols, fast for coalesced stores)
    float acc[8][8];
    #pragma unroll
    for (int i = 0; i < 8; ++i)
        #pragma unroll
        for (int j = 0; j < 8; ++j) acc[i][j] = 0.0f;

    #pragma unroll 4
    for (int k = 0; k < 64; ++k) {
        float4 a0 = At4[k * 32 + tx * 2 + 0];
        float4 a1 = At4[k * 32 + tx * 2 + 1];
        float4 b0 = Bt4[k * 32 + ty];
        float4 b1 = Bt4[k * 32 + 16 + ty];
        float av[8] = {a0.x, a0.y, a0.z, a0.w, a1.x, a1.y, a1.z, a1.w};
        float bw[8] = {b0.x, b0.y, b0.z, b0.w, b1.x, b1.y, b1.z, b1.w};
        #pragma unroll
        for (int i = 0; i < 8; ++i)
            #pragma unroll
            for (int j = 0; j < 8; ++j)
                acc[i][j] += av[i] * bw[j];
    }
    float sqm[8], sqn[8];
    #pragma unroll
    for (int i = 0; i < 8; ++i) sqm[i] = sq[m0 + tx * 8 + i];
    #pragma unroll
    for (int j = 0; j < 4; ++j) {
        sqn[j]     = sq[n0 + ty * 4 + j];
        sqn[4 + j] = sq[n0 + 64 + ty * 4 + j];
    }
    #pragma unroll
    for (int i = 0; i < 8; ++i) {
        size_t rowoff = (size_t)(m0 - rowBase + tx * 8 + i) * 8192;
        float4 w0, w1;
        w0.x = sqm[i] + sqn[0] - 2.0f * acc[i][0];
        w0.y = sqm[i] + sqn[1] - 2.0f * acc[i][1];
        w0.z = sqm[i] + sqn[2] - 2.0f * acc[i][2];
        w0.w = sqm[i] + sqn[3] - 2.0f * acc[i][3];
        w1.x = sqm[i] + sqn[4] - 2.0f * acc[i][4];
        w1.y = sqm[i] + sqn[5] - 2.0f * acc[i][5];
        w1.z = sqm[i] + sqn[6] - 2.0f * acc[i][6];
        w1.w = sqm[i] + sqn[7] - 2.0f * acc[i][7];
        float4* wp = (float4*)(d2 + rowoff + n0);
        wp[ty] = w0;
        wp[16 + ty] = w1;
    }
}

// ---------------- per-row selection of 26 smallest, drop rank-0 -------------
// 4 waves: each wave finds top-26 of its 2048 elems (registers, wave-sync,
// no barriers), then wave 0 merges 104 candidates. Tie-break: smaller index.
__global__ __launch_bounds__(256) void tsa_select_kernel(const float* __restrict__ d2,
                                                         int* __restrict__ nbrs,
                                                         int rowBase) {
    const int t = threadIdx.x;
    const int lane = t & 63;
    const int wv = t >> 6;
    const int i = rowBase + blockIdx.x;
    const float4* row4 = (const float4*)(d2 + (size_t)blockIdx.x * 8192u);

    float v[32];
    #pragma unroll
    for (int r = 0; r < 8; ++r) {
        float4 f = row4[wv * 512 + r * 64 + lane];
        v[4 * r + 0] = f.x; v[4 * r + 1] = f.y;
        v[4 * r + 2] = f.z; v[4 * r + 3] = f.w;
    }
    __shared__ float selV[4][KSEL];
    __shared__ int   selJ[4][KSEL];
    unsigned removed = 0;
    for (int round = 0; round < KSEL; ++round) {
        float bv = 3.0e38f; int bq = 0;
        #pragma unroll
        for (int q = 0; q < 32; ++q) {
            bool ok = ((removed >> q) & 1u) == 0u;
            bool c = ok && (v[q] < bv);
            bv = c ? v[q] : bv;
            bq = c ? q : bq;
        }
        int bj = wv * 2048 + (bq >> 2) * 256 + lane * 4 + (bq & 3);
        #pragma unroll
        for (int off = 1; off < 64; off <<= 1) {
            float rv = __shfl_xor(bv, off);
            int rj = __shfl_xor(bj, off);
            bool take = (rv < bv) || (rv == bv && rj < bj);
            bv = take ? rv : bv;
            bj = take ? rj : bj;
        }
        int jl = bj - wv * 2048;
        int ol = (jl >> 2) & 63;
        int oq = ((jl >> 8) << 2) | (jl & 3);
        if (lane == ol) removed |= (1u << oq);
        if (lane == 0) { selV[wv][round] = bv; selJ[wv][round] = bj; }
    }
    __syncthreads();
    if (wv == 0) {
        bool has = lane < 52;
        int p0 = lane, p1 = lane + 52;
        float v0 = has ? selV[p0 / KSEL][p0 % KSEL] : 3.0e38f;
        int   j0 = has ? selJ[p0 / KSEL][p0 % KSEL] : 0x7ffffffe;
        float v1 = has ? selV[p1 / KSEL][p1 % KSEL] : 3.0e38f;
        int   j1 = has ? selJ[p1 / KSEL][p1 % KSEL] : 0x7ffffffe;
        unsigned rm = 0;
        for (int round = 0; round < KSEL; ++round) {
            float bv = 3.0e38f; int bj = 0x7fffffff;
            if (!(rm & 1u)) { bv = v0; bj = j0; }
            if (!(rm & 2u) && (v1 < bv || (v1 == bv && j1 < bj))) { bv = v1; bj = j1; }
            #pragma unroll
            for (int off = 1; off < 64; off <<= 1) {
                float rv = __shfl_xor(bv, off);
                int rj = __shfl_xor(bj, off);
                bool take = (rv < bv) || (rv == bv && rj < bj);
                bv = take ? rv : bv;
                bj = take ? rj : bj;
            }
            if (bv == v0 && bj == j0) rm |= 1u;
            else if (bv == v1 && bj == j1) rm |= 2u;
            if (lane == 0 && round > 0) nbrs[i * 25 + round - 1] = bj;
        }
    }
}

// ---------------- per-sample eigen + per_sample value -----------------------
// 4 samples per block, one wave per sample. Lanes 0..24 own Gz columns,
// lanes 32..56 own Gx columns. All LDS deps are intra-wave -> no barriers;
// s_waitcnt lgkmcnt(0) orders ds_write -> cross-lane ds_read (per-wave
// in-order LDS queue). gt (stride 28) aliases zx (stride 68) after gram;
// the final u = Zc^T w pass re-reads neighbor rows from global (L2-hot).
__global__ __launch_bounds__(256) void tsa_eigen_kernel(const int* __restrict__ nbrs,
                                                        const float* __restrict__ latent,
                                                        const float* __restrict__ raw,
                                                        float* __restrict__ tsaV) {
    // 8 slices (wv*2+half) x 1700 floats = 54,400 B -> 3 blocks/CU.
    __shared__ __align__(16) float pool[8][1700];
    const int t = threadIdx.x, lane = t & 63, wv = t >> 6;
    const int i = blockIdx.x * 4 + wv;
    const int half = lane >> 5;
    const int b = lane & 31;
    const bool act = b < 25;
    const int bb = act ? b : 0;
    const float* src = half ? raw : latent;
    float* slice = pool[wv * 2 + half];

    // ---- stage own neighbor row (zx view: row b at slice + b*68) ----
    int nb = 0;
    if (act) {
        nb = nbrs[i * 25 + b];
        const float4* s4 = (const float4*)(src + nb * 64);
        float4* dst = (float4*)(slice + b * 68);
        #pragma unroll
        for (int c = 0; c < 16; ++c) dst[c] = s4[c];
    }
    asm volatile("s_waitcnt lgkmcnt(0)" ::: "memory");

    // ---- Gram: g[a] = dot(row a, own row b) ----
    float g[25];
    #pragma unroll
    for (int a = 0; a < 25; ++a) g[a] = 0.0f;
    #pragma unroll 1
    for (int ch = 0; ch < 4; ++ch) {
        float ow[16];
        const float4* op = (const float4*)(slice + bb * 68);
        ((float4*)ow)[0] = op[ch * 4 + 0];
        ((float4*)ow)[1] = op[ch * 4 + 1];
        ((float4*)ow)[2] = op[ch * 4 + 2];
        ((float4*)ow)[3] = op[ch * 4 + 3];
        #pragma unroll
        for (int a = 0; a < 25; ++a) {
            float rr[16];
            const float4* rp = (const float4*)(slice + a * 68);
            ((float4*)rr)[0] = rp[ch * 4 + 0];
            ((float4*)rr)[1] = rp[ch * 4 + 1];
            ((float4*)rr)[2] = rp[ch * 4 + 2];
            ((float4*)rr)[3] = rp[ch * 4 + 3];
            float s = 0.0f;
            #pragma unroll
            for (int d4 = 0; d4 < 16; ++d4) s += ow[d4] * rr[d4];
            g[a] += s;
        }
    }

    // ---- double-centering via shfl (no LDS) ----
    {
        float rs_own = 0.0f;
        #pragma unroll
        for (int a = 0; a < 25; ++a) rs_own += g[a];
        float grand = 0.0f;
        float rsA[25];
        #pragma unroll
        for (int a = 0; a < 25; ++a) {
            rsA[a] = __shfl(rs_own, half * 32 + a);
            grand += rsA[a];
        }
        const float c1 = 1.0f / 25.0f, c2 = 1.0f / 625.0f;
        #pragma unroll
        for (int a = 0; a < 25; ++a)
            g[a] = g[a] - rsA[a] * c1 - rs_own * c1 + grand * c2;
    }

    // ---- 8 trace-normalized squarings (gt view: col c at slice + c*28) ----
    #pragma unroll 1
    for (int rd = 0; rd < ROUNDS; ++rd) {
        float ss = 0.0f;
        #pragma unroll
        for (int r2 = 0; r2 < 25; ++r2) ss += g[r2] * g[r2];
        ss = act ? ss : 0.0f;
        #pragma unroll
        for (int off = 1; off < 32; off <<= 1) ss += __shfl_xor(ss, off);
        float inv = 1.0f / ss;
        if (act) {
            float4* gw = (float4*)(slice + b * 28);
            gw[0] = make_float4(g[0], g[1], g[2], g[3]);
            gw[1] = make_float4(g[4], g[5], g[6], g[7]);
            gw[2] = make_float4(g[8], g[9], g[10], g[11]);
            gw[3] = make_float4(g[12], g[13], g[14], g[15]);
            gw[4] = make_float4(g[16], g[17], g[18], g[19]);
            gw[5] = make_float4(g[20], g[21], g[22], g[23]);
            gw[6] = make_float4(g[24], 0.0f, 0.0f, 0.0f);
        }
        asm volatile("s_waitcnt lgkmcnt(0)" ::: "memory");
        float ng[25];
        #pragma unroll
        for (int r2 = 0; r2 < 25; ++r2) ng[r2] = 0.0f;
        #pragma unroll
        for (int c = 0; c < 25; ++c) {
            float cc2[28];
            const float4* gr = (const float4*)(slice + c * 28);
            ((float4*)cc2)[0] = gr[0];
            ((float4*)cc2)[1] = gr[1];
            ((float4*)cc2)[2] = gr[2];
            ((float4*)cc2)[3] = gr[3];
            ((float4*)cc2)[4] = gr[4];
            ((float4*)cc2)[5] = gr[5];
            ((float4*)cc2)[6] = gr[6];
            float m2 = g[c];
            #pragma unroll
            for (int r2 = 0; r2 < 25; ++r2) ng[r2] += cc2[r2] * m2;
        }
        #pragma unroll
        for (int r2 = 0; r2 < 25; ++r2) g[r2] = ng[r2] * inv;
    }

    // ---- final columns to LDS ----
    if (act) {
        float4* gw = (float4*)(slice + b * 28);
        gw[0] = make_float4(g[0], g[1], g[2], g[3]);
        gw[1] = make_float4(g[4], g[5], g[6], g[7]);
        gw[2] = make_float4(g[8], g[9], g[10], g[11]);
        gw[3] = make_float4(g[12], g[13], g[14], g[15]);
        gw[4] = make_float4(g[16], g[17], g[18], g[19]);
        gw[5] = make_float4(g[20], g[21], g[22], g[23]);
        gw[6] = make_float4(g[24], 0.0f, 0.0f, 0.0f);
    }
    asm volatile("s_waitcnt lgkmcnt(0)" ::: "memory");

    // ---- argmax of diagonal per half -> best-conditioned column ----
    float dv = act ? slice[b * 28 + b] : -1.0f;
    int bi = b;
    #pragma unroll
    for (int off = 1; off < 32; off <<= 1) {
        float ov = __shfl_xor(dv, off);
        int oi = __shfl_xor(bi, off);
        bool take = (ov > dv) || (ov == dv && oi < bi);
        dv = take ? ov : dv;
        bi = take ? oi : bi;
    }
    int jz = __shfl(bi, 0);
    int jxm = __shfl(bi, 32);

    const float* slice0 = pool[wv * 2 + 0];
    const float* slice1 = pool[wv * 2 + 1];
    float wzArr[28], wxArr[28];
    {
        const float4* wz4 = (const float4*)(slice0 + jz * 28);
        const float4* wx4 = (const float4*)(slice1 + jxm * 28);
        #pragma unroll
        for (int q = 0; q < 7; ++q) {
            ((float4*)wzArr)[q] = wz4[q];
            ((float4*)wxArr)[q] = wx4[q];
        }
    }
    float szs = 0.0f, sxs = 0.0f;
    #pragma unroll
    for (int k = 0; k < 25; ++k) { szs += wzArr[k]; sxs += wxArr[k]; }
    float azc = szs * (1.0f / 25.0f), axc = sxs * (1.0f / 25.0f);

    // u[d] = sum_k Z[k][d] (w[k]-mean(w)); rows re-read from global (L2-hot).
    float uz = 0.0f, ux = 0.0f;
    #pragma unroll
    for (int k = 0; k < 25; ++k) {
        int nbz = __shfl(nb, k);
        int nbx = __shfl(nb, 32 + k);
        uz += latent[nbz * 64 + lane] * (wzArr[k] - azc);
        ux += raw[nbx * 64 + lane] * (wxArr[k] - axc);
    }
    float aa = uz * uz, bbv = ux * ux, ccv = uz * ux;
    #pragma unroll
    for (int off = 1; off < 64; off <<= 1) {
        aa += __shfl_xor(aa, off);
        bbv += __shfl_xor(bbv, off);
        ccv += __shfl_xor(ccv, off);
    }
    if (lane == 0) {
        float dot2 = (ccv * ccv) / fmaxf(aa * bbv, 1e-30f);
        tsaV[i] = 2.0f - 2.0f * dot2;
    }
}

// ---------------- final: out = recon/524288 + 0.1*mean(tsaV) ----------------
__global__ __launch_bounds__(256) void tsa_final_kernel(const float* __restrict__ tsaV,
                                                        const float* __restrict__ reconS,
                                                        float* __restrict__ out) {
    float s = 0.0f;
    const float4* v4 = (const float4*)tsaV;
    for (int e = threadIdx.x; e < 2048; e += 256) {
        float4 v = v4[e];
        s += (v.x + v.y) + (v.z + v.w);
    }
    #pragma unroll
    for (int off = 1; off < 64; off <<= 1) s += __shfl_xor(s, off);
    __shared__ float ps[4];
    if ((threadIdx.x & 63) == 0) ps[threadIdx.x >> 6] = s;
    __syncthreads();
    if (threadIdx.x == 0) {
        float tot = ps[0] + ps[1] + ps[2] + ps[3];
        out[0] = reconS[0] * (1.0f / 524288.0f) + 0.1f * (tot * (1.0f / 8192.0f));
    }
}

extern "C" void kernel_launch(void* const* d_in, const int* in_sizes, int n_in,
                              void* d_out, int out_size, void* d_ws, size_t ws_size,
                              hipStream_t stream) {
    const float* outputs = (const float*)d_in[0];
    const float* targets = (const float*)d_in[1];
    const float* latent  = (const float*)d_in[2];
    const float* raw     = (const float*)d_in[3];

    float* ws = (float*)d_ws;
    // ws layout (floats), all offsets 64B-aligned:
    float* sq     = ws;                       // 8192
    float* rawT   = ws + 8192;                // 524288
    int*   nbrs   = (int*)(ws + 532480);      // 8192*25 ints
    float* reconS = ws + 737280;              // 1 (+pad)
    float* tsaV   = ws + 737296;              // 8192
    float* d2buf  = ws + 745728;              // R * 8192

    size_t availF = ws_size / 4;
    // Cap chunk at 2048 rows (64 MB) so the d2 chunk stays L3-resident;
    // halve further if the workspace is smaller.
    int R = 2048;
    while (R > 128 && (size_t)745728 + (size_t)R * 8192 > availF) R >>= 1;

    tsa_sq_kernel<<<2048, 256, 0, stream>>>(raw, sq, reconS);
    tsa_transpose_kernel<<<128, 256, 0, stream>>>(raw, rawT);
    tsa_recon_kernel<<<512, 256, 0, stream>>>(outputs, targets, reconS);

    for (int rb = 0; rb < 8192; rb += R) {
        dim3 g(64, R / 128);
        tsa_dist_kernel<<<g, 256, 0, stream>>>(rawT, sq, d2buf, rb);
        tsa_select_kernel<<<R, 256, 0, stream>>>(d2buf, nbrs, rb);
    }
    tsa_eigen_kernel<<<2048, 256, 0, stream>>>(nbrs, latent, raw, tsaV);
    tsa_final_kernel<<<1, 256, 0, stream>>>(tsaV, reconS, (float*)d_out);
}

// Round 9
// 710.814 us; speedup vs baseline: 1.0664x; 1.0405x over previous
//
#include <hip/hip_runtime.h>
#include <hip/hip_bf16.h>

// TSA loss for MI355X.
// loss = mean((outputs-targets)^2) + 0.1 * mean_b( || Pz_b - Px_b ||_F^2 )
// where Pz/Px are rank-1 projectors onto the top eigenvector of the 25-NN
// covariance of latent/raw. Using ||uu^T - vv^T||^2 = 2(1-(u.v)^2), the Gram
// trick (25x25 instead of 64x64), double-centering of the Gram, and top
// eigenvector via 8 trace-normalized matrix squarings (power 256).
// d2 is chunked at 2048 rows (64 MB) so each chunk stays L3-resident.
// Eigen kernel: barrier-free (intra-wave LDS deps; s_waitcnt lgkmcnt(0)),
// gt aliases zx. Slice = 1696 floats -> pool 54,272 B (53.0 KB exactly;
// 3x54,272 = 162,816 <= 163,840) -> 3 blocks/CU. (1700 floats rounded to
// 54,784 by the 512-B LDS granularity and fell back to 2 blocks/CU.)

#define NB 8192
#define ND 64
#define KSEL 26
#define ROUNDS 8

// ---------------- fused prep: sq | transpose | recon partials --------------
// blocks [0,2048): sq[i] = sum_d raw[i][d]^2        (4 rows/block)
// blocks [2048,2176): rawT[k][i] = raw[i][k]        (64 rows/block)
// blocks [2176,2688): reconP[b] = block partial of sum((o-t)^2)
__global__ __launch_bounds__(256) void tsa_prep_kernel(const float* __restrict__ raw,
                                                       const float* __restrict__ outputs,
                                                       const float* __restrict__ targets,
                                                       float* __restrict__ sq,
                                                       float* __restrict__ rawT,
                                                       float* __restrict__ reconP) {
    __shared__ float tile[64][65];
    const int bid = blockIdx.x;
    const int t = threadIdx.x;
    if (bid < 2048) {
        int row = bid * 4 + (t >> 6);
        int lane = t & 63;
        float v = raw[row * 64 + lane];
        float s = v * v;
        #pragma unroll
        for (int off = 1; off < 64; off <<= 1) s += __shfl_xor(s, off);
        if (lane == 0) sq[row] = s;
    } else if (bid < 2176) {
        int r0 = (bid - 2048) * 64;
        #pragma unroll
        for (int r = 0; r < 4; ++r) {
            int e = r * 256 + t;
            int m = e >> 4, c4 = e & 15;
            float4 v = ((const float4*)raw)[(r0 + m) * 16 + c4];
            tile[m][c4 * 4 + 0] = v.x; tile[m][c4 * 4 + 1] = v.y;
            tile[m][c4 * 4 + 2] = v.z; tile[m][c4 * 4 + 3] = v.w;
        }
        __syncthreads();
        #pragma unroll
        for (int r = 0; r < 4; ++r) {
            int e = r * 256 + t;
            int k = e >> 4, c4 = e & 15;
            float4 v;
            v.x = tile[c4 * 4 + 0][k]; v.y = tile[c4 * 4 + 1][k];
            v.z = tile[c4 * 4 + 2][k]; v.w = tile[c4 * 4 + 3][k];
            ((float4*)rawT)[k * 2048 + (r0 >> 2) + c4] = v;
        }
    } else {
        int idx = (bid - 2176) * 256 + t;
        float4 a = ((const float4*)outputs)[idx];
        float4 b = ((const float4*)targets)[idx];
        float dx = a.x - b.x, dy = a.y - b.y, dz = a.z - b.z, dw = a.w - b.w;
        float s = dx * dx + dy * dy + dz * dz + dw * dw;
        #pragma unroll
        for (int off = 1; off < 64; off <<= 1) s += __shfl_xor(s, off);
        __shared__ float ps[4];
        if ((t & 63) == 0) ps[t >> 6] = s;
        __syncthreads();
        if (t == 0) reconP[bid - 2176] = ps[0] + ps[1] + ps[2] + ps[3];
    }
}

// ---------------- distance tile GEMM: d2[i][j] = sq[i]+sq[j]-2*dot ----------
// 128x128 tile, 256 threads, 8x8 per thread, K=64 single shot.
__global__ __launch_bounds__(256) void tsa_dist_kernel(const float* __restrict__ rawT,
                                                       const float* __restrict__ sq,
                                                       float* __restrict__ d2,
                                                       int rowBase) {
    __shared__ float At[64 * 128];
    __shared__ float Bt[64 * 128];
    const int t = threadIdx.x;
    const int m0 = rowBase + blockIdx.y * 128;
    const int n0 = blockIdx.x * 128;
    const float4* rT4 = (const float4*)rawT;
    float4* At4 = (float4*)At;
    float4* Bt4 = (float4*)Bt;
    #pragma unroll
    for (int r = 0; r < 8; ++r) {
        int e = r * 256 + t;
        int k = e >> 5, c = e & 31;
        At4[e] = rT4[k * 2048 + (m0 >> 2) + c];
        Bt4[e] = rT4[k * 2048 + (n0 >> 2) + c];
    }
    __syncthreads();
    const int tx = t >> 4;   // m-block (rows)
    const int ty = t & 15;   // n-block (cols, fast for coalesced stores)
    float acc[8][8];
    #pragma unroll
    for (int i = 0; i < 8; ++i)
        #pragma unroll
        for (int j = 0; j < 8; ++j) acc[i][j] = 0.0f;

    #pragma unroll 4
    for (int k = 0; k < 64; ++k) {
        float4 a0 = At4[k * 32 + tx * 2 + 0];
        float4 a1 = At4[k * 32 + tx * 2 + 1];
        float4 b0 = Bt4[k * 32 + ty];
        float4 b1 = Bt4[k * 32 + 16 + ty];
        float av[8] = {a0.x, a0.y, a0.z, a0.w, a1.x, a1.y, a1.z, a1.w};
        float bw[8] = {b0.x, b0.y, b0.z, b0.w, b1.x, b1.y, b1.z, b1.w};
        #pragma unroll
        for (int i = 0; i < 8; ++i)
            #pragma unroll
            for (int j = 0; j < 8; ++j)
                acc[i][j] += av[i] * bw[j];
    }
    float sqm[8], sqn[8];
    #pragma unroll
    for (int i = 0; i < 8; ++i) sqm[i] = sq[m0 + tx * 8 + i];
    #pragma unroll
    for (int j = 0; j < 4; ++j) {
        sqn[j]     = sq[n0 + ty * 4 + j];
        sqn[4 + j] = sq[n0 + 64 + ty * 4 + j];
    }
    #pragma unroll
    for (int i = 0; i < 8; ++i) {
        size_t rowoff = (size_t)(m0 - rowBase + tx * 8 + i) * 8192;
        float4 w0, w1;
        w0.x = sqm[i] + sqn[0] - 2.0f * acc[i][0];
        w0.y = sqm[i] + sqn[1] - 2.0f * acc[i][1];
        w0.z = sqm[i] + sqn[2] - 2.0f * acc[i][2];
        w0.w = sqm[i] + sqn[3] - 2.0f * acc[i][3];
        w1.x = sqm[i] + sqn[4] - 2.0f * acc[i][4];
        w1.y = sqm[i] + sqn[5] - 2.0f * acc[i][5];
        w1.z = sqm[i] + sqn[6] - 2.0f * acc[i][6];
        w1.w = sqm[i] + sqn[7] - 2.0f * acc[i][7];
        float4* wp = (float4*)(d2 + rowoff + n0);
        wp[ty] = w0;
        wp[16 + ty] = w1;
    }
}

// ---------------- per-row selection of 26 smallest, drop rank-0 -------------
// 4 waves: each wave finds top-26 of its 2048 elems (registers, wave-sync,
// no barriers), then wave 0 merges 104 candidates. Tie-break: smaller index.
__global__ __launch_bounds__(256) void tsa_select_kernel(const float* __restrict__ d2,
                                                         int* __restrict__ nbrs,
                                                         int rowBase) {
    const int t = threadIdx.x;
    const int lane = t & 63;
    const int wv = t >> 6;
    const int i = rowBase + blockIdx.x;
    const float4* row4 = (const float4*)(d2 + (size_t)blockIdx.x * 8192u);

    float v[32];
    #pragma unroll
    for (int r = 0; r < 8; ++r) {
        float4 f = row4[wv * 512 + r * 64 + lane];
        v[4 * r + 0] = f.x; v[4 * r + 1] = f.y;
        v[4 * r + 2] = f.z; v[4 * r + 3] = f.w;
    }
    __shared__ float selV[4][KSEL];
    __shared__ int   selJ[4][KSEL];
    unsigned removed = 0;
    for (int round = 0; round < KSEL; ++round) {
        float bv = 3.0e38f; int bq = 0;
        #pragma unroll
        for (int q = 0; q < 32; ++q) {
            bool ok = ((removed >> q) & 1u) == 0u;
            bool c = ok && (v[q] < bv);
            bv = c ? v[q] : bv;
            bq = c ? q : bq;
        }
        int bj = wv * 2048 + (bq >> 2) * 256 + lane * 4 + (bq & 3);
        #pragma unroll
        for (int off = 1; off < 64; off <<= 1) {
            float rv = __shfl_xor(bv, off);
            int rj = __shfl_xor(bj, off);
            bool take = (rv < bv) || (rv == bv && rj < bj);
            bv = take ? rv : bv;
            bj = take ? rj : bj;
        }
        int jl = bj - wv * 2048;
        int ol = (jl >> 2) & 63;
        int oq = ((jl >> 8) << 2) | (jl & 3);
        if (lane == ol) removed |= (1u << oq);
        if (lane == 0) { selV[wv][round] = bv; selJ[wv][round] = bj; }
    }
    __syncthreads();
    if (wv == 0) {
        bool has = lane < 52;
        int p0 = lane, p1 = lane + 52;
        float v0 = has ? selV[p0 / KSEL][p0 % KSEL] : 3.0e38f;
        int   j0 = has ? selJ[p0 / KSEL][p0 % KSEL] : 0x7ffffffe;
        float v1 = has ? selV[p1 / KSEL][p1 % KSEL] : 3.0e38f;
        int   j1 = has ? selJ[p1 / KSEL][p1 % KSEL] : 0x7ffffffe;
        unsigned rm = 0;
        for (int round = 0; round < KSEL; ++round) {
            float bv = 3.0e38f; int bj = 0x7fffffff;
            if (!(rm & 1u)) { bv = v0; bj = j0; }
            if (!(rm & 2u) && (v1 < bv || (v1 == bv && j1 < bj))) { bv = v1; bj = j1; }
            #pragma unroll
            for (int off = 1; off < 64; off <<= 1) {
                float rv = __shfl_xor(bv, off);
                int rj = __shfl_xor(bj, off);
                bool take = (rv < bv) || (rv == bv && rj < bj);
                bv = take ? rv : bv;
                bj = take ? rj : bj;
            }
            if (bv == v0 && bj == j0) rm |= 1u;
            else if (bv == v1 && bj == j1) rm |= 2u;
            if (lane == 0 && round > 0) nbrs[i * 25 + round - 1] = bj;
        }
    }
}

// ---------------- per-sample eigen + per_sample value -----------------------
// 4 samples per block, one wave per sample. Lanes 0..24 own Gz columns,
// lanes 32..56 own Gx columns. All LDS deps are intra-wave -> no barriers;
// s_waitcnt lgkmcnt(0) orders ds_write -> cross-lane ds_read (per-wave
// in-order LDS queue). gt (stride 28) aliases zx (stride 68) after gram;
// the final u = Zc^T w pass re-reads neighbor rows from global (L2-hot).
__global__ __launch_bounds__(256) void tsa_eigen_kernel(const int* __restrict__ nbrs,
                                                        const float* __restrict__ latent,
                                                        const float* __restrict__ raw,
                                                        float* __restrict__ tsaV) {
    // 8 slices x 1696 floats = 54,272 B (53.0 KB) -> 3 blocks/CU.
    // max live index per slice: 24*68 + 64 = 1696 (row stride 68, 25 rows).
    __shared__ __align__(16) float pool[8][1696];
    const int t = threadIdx.x, lane = t & 63, wv = t >> 6;
    const int i = blockIdx.x * 4 + wv;
    const int half = lane >> 5;
    const int b = lane & 31;
    const bool act = b < 25;
    const int bb = act ? b : 0;
    const float* src = half ? raw : latent;
    float* slice = pool[wv * 2 + half];

    // ---- stage own neighbor row (zx view: row b at slice + b*68) ----
    int nb = 0;
    if (act) {
        nb = nbrs[i * 25 + b];
        const float4* s4 = (const float4*)(src + nb * 64);
        float4* dst = (float4*)(slice + b * 68);
        #pragma unroll
        for (int c = 0; c < 16; ++c) dst[c] = s4[c];
    }
    asm volatile("s_waitcnt lgkmcnt(0)" ::: "memory");

    // ---- Gram: g[a] = dot(row a, own row b) ----
    float g[25];
    #pragma unroll
    for (int a = 0; a < 25; ++a) g[a] = 0.0f;
    #pragma unroll 1
    for (int ch = 0; ch < 4; ++ch) {
        float ow[16];
        const float4* op = (const float4*)(slice + bb * 68);
        ((float4*)ow)[0] = op[ch * 4 + 0];
        ((float4*)ow)[1] = op[ch * 4 + 1];
        ((float4*)ow)[2] = op[ch * 4 + 2];
        ((float4*)ow)[3] = op[ch * 4 + 3];
        #pragma unroll
        for (int a = 0; a < 25; ++a) {
            float rr[16];
            const float4* rp = (const float4*)(slice + a * 68);
            ((float4*)rr)[0] = rp[ch * 4 + 0];
            ((float4*)rr)[1] = rp[ch * 4 + 1];
            ((float4*)rr)[2] = rp[ch * 4 + 2];
            ((float4*)rr)[3] = rp[ch * 4 + 3];
            float s = 0.0f;
            #pragma unroll
            for (int d4 = 0; d4 < 16; ++d4) s += ow[d4] * rr[d4];
            g[a] += s;
        }
    }

    // ---- double-centering via shfl (no LDS) ----
    {
        float rs_own = 0.0f;
        #pragma unroll
        for (int a = 0; a < 25; ++a) rs_own += g[a];
        float grand = 0.0f;
        float rsA[25];
        #pragma unroll
        for (int a = 0; a < 25; ++a) {
            rsA[a] = __shfl(rs_own, half * 32 + a);
            grand += rsA[a];
        }
        const float c1 = 1.0f / 25.0f, c2 = 1.0f / 625.0f;
        #pragma unroll
        for (int a = 0; a < 25; ++a)
            g[a] = g[a] - rsA[a] * c1 - rs_own * c1 + grand * c2;
    }

    // ---- 8 trace-normalized squarings (gt view: col c at slice + c*28) ----
    #pragma unroll 1
    for (int rd = 0; rd < ROUNDS; ++rd) {
        float ss = 0.0f;
        #pragma unroll
        for (int r2 = 0; r2 < 25; ++r2) ss += g[r2] * g[r2];
        ss = act ? ss : 0.0f;
        #pragma unroll
        for (int off = 1; off < 32; off <<= 1) ss += __shfl_xor(ss, off);
        float inv = 1.0f / ss;
        if (act) {
            float4* gw = (float4*)(slice + b * 28);
            gw[0] = make_float4(g[0], g[1], g[2], g[3]);
            gw[1] = make_float4(g[4], g[5], g[6], g[7]);
            gw[2] = make_float4(g[8], g[9], g[10], g[11]);
            gw[3] = make_float4(g[12], g[13], g[14], g[15]);
            gw[4] = make_float4(g[16], g[17], g[18], g[19]);
            gw[5] = make_float4(g[20], g[21], g[22], g[23]);
            gw[6] = make_float4(g[24], 0.0f, 0.0f, 0.0f);
        }
        asm volatile("s_waitcnt lgkmcnt(0)" ::: "memory");
        float ng[25];
        #pragma unroll
        for (int r2 = 0; r2 < 25; ++r2) ng[r2] = 0.0f;
        #pragma unroll
        for (int c = 0; c < 25; ++c) {
            float cc2[28];
            const float4* gr = (const float4*)(slice + c * 28);
            ((float4*)cc2)[0] = gr[0];
            ((float4*)cc2)[1] = gr[1];
            ((float4*)cc2)[2] = gr[2];
            ((float4*)cc2)[3] = gr[3];
            ((float4*)cc2)[4] = gr[4];
            ((float4*)cc2)[5] = gr[5];
            ((float4*)cc2)[6] = gr[6];
            float m2 = g[c];
            #pragma unroll
            for (int r2 = 0; r2 < 25; ++r2) ng[r2] += cc2[r2] * m2;
        }
        #pragma unroll
        for (int r2 = 0; r2 < 25; ++r2) g[r2] = ng[r2] * inv;
    }

    // ---- final columns to LDS ----
    if (act) {
        float4* gw = (float4*)(slice + b * 28);
        gw[0] = make_float4(g[0], g[1], g[2], g[3]);
        gw[1] = make_float4(g[4], g[5], g[6], g[7]);
        gw[2] = make_float4(g[8], g[9], g[10], g[11]);
        gw[3] = make_float4(g[12], g[13], g[14], g[15]);
        gw[4] = make_float4(g[16], g[17], g[18], g[19]);
        gw[5] = make_float4(g[20], g[21], g[22], g[23]);
        gw[6] = make_float4(g[24], 0.0f, 0.0f, 0.0f);
    }
    asm volatile("s_waitcnt lgkmcnt(0)" ::: "memory");

    // ---- argmax of diagonal per half -> best-conditioned column ----
    float dv = act ? slice[b * 28 + b] : -1.0f;
    int bi = b;
    #pragma unroll
    for (int off = 1; off < 32; off <<= 1) {
        float ov = __shfl_xor(dv, off);
        int oi = __shfl_xor(bi, off);
        bool take = (ov > dv) || (ov == dv && oi < bi);
        dv = take ? ov : dv;
        bi = take ? oi : bi;
    }
    int jz = __shfl(bi, 0);
    int jxm = __shfl(bi, 32);

    const float* slice0 = pool[wv * 2 + 0];
    const float* slice1 = pool[wv * 2 + 1];
    float wzArr[28], wxArr[28];
    {
        const float4* wz4 = (const float4*)(slice0 + jz * 28);
        const float4* wx4 = (const float4*)(slice1 + jxm * 28);
        #pragma unroll
        for (int q = 0; q < 7; ++q) {
            ((float4*)wzArr)[q] = wz4[q];
            ((float4*)wxArr)[q] = wx4[q];
        }
    }
    float szs = 0.0f, sxs = 0.0f;
    #pragma unroll
    for (int k = 0; k < 25; ++k) { szs += wzArr[k]; sxs += wxArr[k]; }
    float azc = szs * (1.0f / 25.0f), axc = sxs * (1.0f / 25.0f);

    // u[d] = sum_k Z[k][d] (w[k]-mean(w)); rows re-read from global (L2-hot).
    float uz = 0.0f, ux = 0.0f;
    #pragma unroll
    for (int k = 0; k < 25; ++k) {
        int nbz = __shfl(nb, k);
        int nbx = __shfl(nb, 32 + k);
        uz += latent[nbz * 64 + lane] * (wzArr[k] - azc);
        ux += raw[nbx * 64 + lane] * (wxArr[k] - axc);
    }
    float aa = uz * uz, bbv = ux * ux, ccv = uz * ux;
    #pragma unroll
    for (int off = 1; off < 64; off <<= 1) {
        aa += __shfl_xor(aa, off);
        bbv += __shfl_xor(bbv, off);
        ccv += __shfl_xor(ccv, off);
    }
    if (lane == 0) {
        float dot2 = (ccv * ccv) / fmaxf(aa * bbv, 1e-30f);
        tsaV[i] = 2.0f - 2.0f * dot2;
    }
}

// ---------------- final: out = sum(reconP)/524288 + 0.1*mean(tsaV) ----------
__global__ __launch_bounds__(256) void tsa_final_kernel(const float* __restrict__ tsaV,
                                                        const float* __restrict__ reconP,
                                                        float* __restrict__ out) {
    const int t = threadIdx.x;
    float s = 0.0f;
    const float4* v4 = (const float4*)tsaV;
    for (int e = t; e < 2048; e += 256) {
        float4 v = v4[e];
        s += (v.x + v.y) + (v.z + v.w);
    }
    float r = 0.0f;
    if (t < 128) {
        float4 p = ((const float4*)reconP)[t];
        r = (p.x + p.y) + (p.z + p.w);
    }
    #pragma unroll
    for (int off = 1; off < 64; off <<= 1) {
        s += __shfl_xor(s, off);
        r += __shfl_xor(r, off);
    }
    __shared__ float ps[4], pr[4];
    if ((t & 63) == 0) { ps[t >> 6] = s; pr[t >> 6] = r; }
    __syncthreads();
    if (t == 0) {
        float tot = ps[0] + ps[1] + ps[2] + ps[3];
        float rec = pr[0] + pr[1] + pr[2] + pr[3];
        out[0] = rec * (1.0f / 524288.0f) + 0.1f * (tot * (1.0f / 8192.0f));
    }
}

extern "C" void kernel_launch(void* const* d_in, const int* in_sizes, int n_in,
                              void* d_out, int out_size, void* d_ws, size_t ws_size,
                              hipStream_t stream) {
    const float* outputs = (const float*)d_in[0];
    const float* targets = (const float*)d_in[1];
    const float* latent  = (const float*)d_in[2];
    const float* raw     = (const float*)d_in[3];

    float* ws = (float*)d_ws;
    // ws layout (floats), all offsets 64B-aligned:
    float* sq     = ws;                       // 8192
    float* rawT   = ws + 8192;                // 524288
    int*   nbrs   = (int*)(ws + 532480);      // 8192*25 ints -> ends 737280
    float* reconP = ws + 737280;              // 512
    float* tsaV   = ws + 737792;              // 8192 -> ends 745984
    float* d2buf  = ws + 745984;              // R * 8192

    size_t availF = ws_size / 4;
    // Cap chunk at 2048 rows (64 MB) so the d2 chunk stays L3-resident;
    // halve further if the workspace is smaller.
    int R = 2048;
    while (R > 128 && (size_t)745984 + (size_t)R * 8192 > availF) R >>= 1;

    tsa_prep_kernel<<<2688, 256, 0, stream>>>(raw, outputs, targets, sq, rawT, reconP);

    for (int rb = 0; rb < 8192; rb += R) {
        dim3 g(64, R / 128);
        tsa_dist_kernel<<<g, 256, 0, stream>>>(rawT, sq, d2buf, rb);
        tsa_select_kernel<<<R, 256, 0, stream>>>(d2buf, nbrs, rb);
    }
    tsa_eigen_kernel<<<2048, 256, 0, stream>>>(nbrs, latent, raw, tsaV);
    tsa_final_kernel<<<1, 256, 0, stream>>>(tsaV, reconP, (float*)d_out);
}